// Round 18
// baseline (176.902 us; speedup 1.0000x reference)
//
#include <hip/hip_runtime.h>
#include <hip/hip_bf16.h>

// Problem constants
#define NB   32      // batch
#define NC   24      // image channels
#define ND   12      // spatial
#define NN   144     // ND*ND objects
#define QD   11
#define GH   256
#define FOUT 10

typedef unsigned short u16;
typedef __attribute__((ext_vector_type(8))) short bf16x8;
typedef __attribute__((ext_vector_type(4))) float f32x4;

// Workspace layout (u16 units unless noted):
//   Lqb  u16 [32][144][256]  off 0          (= L + q@Wg1_q + bg1, bf16)
//   Rb   u16 [32][144][256]  off 1179648
//   Bswz u16 [128][64][8]    off 2359296    (16x16x32 B-fragment order)
//   S    f32 [32][256]       byte-off 4849664
#define LQ_U16  0
#define R_U16   1179648
#define BS_U16  2359296
#define S_BYTE  4849664

__device__ inline float b2f(u16 v) {
  union { unsigned u; float f; } c; c.u = ((unsigned)v) << 16; return c.f;
}
__device__ inline u16 f2b(float f) {
  __hip_bfloat16 h = __float2bfloat16(f);
  return *reinterpret_cast<u16*>(&h);
}

// ---------------------------------------------------------------------------
// prep v2 (proven r17): Wg1 in registers; blocks [0,256) projections,
// blocks [256,512) Wg2 B-fragment swizzle + zero S.
// ---------------------------------------------------------------------------
__global__ __launch_bounds__(256) void prep(const float* __restrict__ image,
                                            const float* __restrict__ question,
                                            const float* __restrict__ Wg1,
                                            const float* __restrict__ bg1,
                                            const float* __restrict__ Wg2,
                                            u16* __restrict__ Lq,
                                            u16* __restrict__ R,
                                            float* __restrict__ S,
                                            u16* __restrict__ Bswz) {
  int blk = blockIdx.x;
  int h   = threadIdx.x;
  if (blk < 256) {
    const int quarter = blk & 3;
    const int b       = (blk >> 2) & 31;
    const int which   = blk >> 7;
    float Wl[NC + 2];
#pragma unroll
    for (int r = 0; r < NC + 2; ++r)
      Wl[r] = Wg1[(which * (NC + 2) + r) * GH + h];
    float qacc = 0.f;
    if (which == 0) {
      qacc = bg1[h];
#pragma unroll
      for (int tq = 0; tq < QD; ++tq)
        qacc += question[b * QD + tq] * Wg1[(2 * (NC + 2) + tq) * GH + h];
    }
    const float* img = image + b * (NC * NN);
    u16* dst = (which == 0 ? Lq : R) + b * NN * GH + h;
    const float inv = 1.0f / (ND - 1);
#pragma unroll 4
    for (int p = quarter * 36; p < quarter * 36 + 36; ++p) {
      float acc = qacc;
#pragma unroll
      for (int c = 0; c < NC; ++c) acc += img[c * NN + p] * Wl[c];
      int i = p / ND, j = p - i * ND;
      acc += (j * inv) * Wl[24];
      acc += (i * inv) * Wl[25];
      dst[p * GH] = f2b(acc);
    }
  } else {
    int tid = (blk - 256) * 256 + h;   // 0..65535
    int e   = tid & 7;
    int l   = (tid >> 3) & 63;
    int fid = tid >> 9;
    int kt  = fid >> 4, nt = fid & 15;
    int k = kt * 32 + ((l >> 4) << 3) + e;
    int n = (nt << 4) + (l & 15);
    Bswz[tid] = f2b(Wg2[k * GH + n]);
    if (tid < NB * GH) S[tid] = 0.f;
  }
}

// ---------------------------------------------------------------------------
// MFMA pair GEMM v18: PRODUCER-CONSUMER WAVE SPECIALIZATION.
// Block = 512 thr: waves 0-3 = consumers (each: all 128 rows x 64 cols,
// acc[8][4] in AGPRs + ~70 arch VGPRs), waves 4-7 = producers (each thread
// builds one row-half = 16 octets; ~50 transient VGPRs). Roles never mix ->
// each fits the 128-arch-VGPR budget by construction.
// LDS: 2 x 64 KB A-tile double buffer (128 KB, 1 block/CU). Per tile ONE
// barrier: consumers mma buf[cur] WHILE producers build buf[cur^1] -- VALU
// and matrix pipes run concurrently on different waves (m114).
// Producer wall ~1.3k cyc/tile << consumer 5k: matrix pipe never starves.
// Grid = 256 blocks (1/CU) XCD-pinned; ~20 tiles/block.
// ---------------------------------------------------------------------------
__global__ __launch_bounds__(512, 1) void pair_gemm(const u16* __restrict__ Lq,
                                                    const u16* __restrict__ R,
                                                    const u16* __restrict__ Bswz,
                                                    const float* __restrict__ bg2,
                                                    float* __restrict__ S) {
  const int bid = blockIdx.x;          // 0..255
  const int xcd = bid & 7;
  const int idx = bid >> 3;            // 0..31
  const int b   = xcd * 4 + (idx >> 3);
  const int bi  = idx & 7;             // 8 blocks per batch, 162 tiles
  const int t0  = bi * 20 + (bi < 2 ? bi : 2);
  const int cnt = 20 + (bi < 2 ? 1 : 0);

  // [buf 2][kt 8][mf 8][lane 64][8 bf16] = 128 KB
  __shared__ __align__(16) u16 As[2][32768];

  const int t = threadIdx.x;
  const int w = t >> 6, l = t & 63;

  const u16* Lbase = Lq + b * NN * GH;
  const u16* Rbase = R + b * NN * GH;

  if (w >= 4) {
    // ================= PRODUCER waves =================
    const int tl    = t & 255;
    const int row   = tl >> 1;          // 0..127
    const int khalf = tl & 1;           // which 128-k half (16 octets)
    const int mf_w  = row >> 4;

    // prologue: build tile t0 into As[0]
    {
      int p = t0 * 128 + row;
      int i = p / NN, j = p - i * NN;
      const u16* Lr = Lbase + i * GH + khalf * 128;
      const u16* Rr = Rbase + j * GH + khalf * 128;
#pragma unroll
      for (int u = 0; u < 16; ++u) {
        bf16x8 lv = *(const bf16x8*)(Lr + u * 8);
        bf16x8 rv = *(const bf16x8*)(Rr + u * 8);
        u16 o[8];
#pragma unroll
        for (int e = 0; e < 8; ++e) {
          float v = b2f((u16)lv[e]) + b2f((u16)rv[e]);
          o[e] = f2b(v > 0.f ? v : 0.f);
        }
        const int kt = (khalf << 2) + (u >> 2);
        const int oc = u & 3;
        const int lw = ((row & 15) | (oc << 4)) ^ (oc << 1);
        *(bf16x8*)&As[0][((((kt << 3) | mf_w) << 6) | lw) << 3] = *(bf16x8*)o;
      }
    }
    __syncthreads();

    int cur = 0;
    for (int tt = 0; tt < cnt; ++tt) {
      if (tt + 1 < cnt) {
        int p = (t0 + tt + 1) * 128 + row;
        int i = p / NN, j = p - i * NN;
        const u16* Lr = Lbase + i * GH + khalf * 128;
        const u16* Rr = Rbase + j * GH + khalf * 128;
        u16* dst = &As[cur ^ 1][0];
#pragma unroll
        for (int u = 0; u < 16; ++u) {
          bf16x8 lv = *(const bf16x8*)(Lr + u * 8);
          bf16x8 rv = *(const bf16x8*)(Rr + u * 8);
          u16 o[8];
#pragma unroll
          for (int e = 0; e < 8; ++e) {
            float v = b2f((u16)lv[e]) + b2f((u16)rv[e]);
            o[e] = f2b(v > 0.f ? v : 0.f);
          }
          const int kt = (khalf << 2) + (u >> 2);
          const int oc = u & 3;
          const int lw = ((row & 15) | (oc << 4)) ^ (oc << 1);
          *(bf16x8*)&dst[((((kt << 3) | mf_w) << 6) | lw) << 3] = *(bf16x8*)o;
        }
      }
      __syncthreads();
      cur ^= 1;
    }
  } else {
    // ================= CONSUMER waves =================
    const int lane_r = l ^ (((l >> 4) & 3) << 1);
    const u16* Bl = Bswz + l * 8;

    float bgv[4];
#pragma unroll
    for (int nt = 0; nt < 4; ++nt)
      bgv[nt] = bg2[(w << 6) + (nt << 4) + (l & 15)];
    float ssum[4] = {0.f, 0.f, 0.f, 0.f};

    __syncthreads();                    // matches producer prologue barrier

    int cur = 0;
    for (int tt = 0; tt < cnt; ++tt) {
      const u16* src = &As[cur][0];
      f32x4 acc[8][4] = {};
#pragma unroll
      for (int kt = 0; kt < 8; ++kt) {
        bf16x8 bfr[4];
#pragma unroll
        for (int nt = 0; nt < 4; ++nt) {
          int fid = (kt << 4) | (w << 2) | nt;
          bfr[nt] = *(const bf16x8*)(Bl + ((size_t)fid << 9));
        }
#pragma unroll
        for (int mf = 0; mf < 8; ++mf) {
          bf16x8 af = *(const bf16x8*)
              &src[((((kt << 3) | mf) << 6) | lane_r) << 3];
#pragma unroll
          for (int nt = 0; nt < 4; ++nt)
            acc[mf][nt] = __builtin_amdgcn_mfma_f32_16x16x32_bf16(
                af, bfr[nt], acc[mf][nt], 0, 0, 0);
        }
      }
      // epilogue: fold relu(acc + bg2) into running sums
#pragma unroll
      for (int nt = 0; nt < 4; ++nt) {
        float s = 0.f;
#pragma unroll
        for (int mf = 0; mf < 8; ++mf)
#pragma unroll
          for (int r = 0; r < 4; ++r) {
            float v = acc[mf][nt][r] + bgv[nt];
            s += v > 0.f ? v : 0.f;
          }
        ssum[nt] += s;
      }
      __syncthreads();
      cur ^= 1;
    }

    // Final reduce: C/D col = l&15; shfl-reduce rows, one atomic per slice
    float* Sb = S + b * GH;
#pragma unroll
    for (int nt = 0; nt < 4; ++nt) {
      float s = ssum[nt];
      s += __shfl_xor(s, 16, 64);
      s += __shfl_xor(s, 32, 64);
      if (l < 16) atomicAdd(&Sb[(w << 6) + (nt << 4) + l], s);
    }
  }
}

// ---------------------------------------------------------------------------
// Final f-MLP: out = relu(S@Wf1+bf1)@Wf2+bf2. One block per batch.
// ---------------------------------------------------------------------------
__global__ __launch_bounds__(256) void final_mlp(const float* __restrict__ S,
                                                 const float* __restrict__ Wf1,
                                                 const float* __restrict__ bf1,
                                                 const float* __restrict__ Wf2,
                                                 const float* __restrict__ bf2,
                                                 float* __restrict__ out) {
  __shared__ float sS[GH];
  __shared__ float oS[GH];
  int b = blockIdx.x, h = threadIdx.x;
  sS[h] = S[b * GH + h];
  __syncthreads();
  float acc = bf1[h];
#pragma unroll 8
  for (int k = 0; k < GH; ++k) acc += sS[k] * Wf1[k * GH + h];
  oS[h] = acc > 0.f ? acc : 0.f;
  __syncthreads();
  if (h < FOUT) {
    float o = bf2[h];
#pragma unroll 8
    for (int k = 0; k < GH; ++k) o += oS[k] * Wf2[k * FOUT + h];
    out[b * FOUT + h] = o;
  }
}

extern "C" void kernel_launch(void* const* d_in, const int* in_sizes, int n_in,
                              void* d_out, int out_size, void* d_ws, size_t ws_size,
                              hipStream_t stream) {
  const float* image    = (const float*)d_in[0];
  const float* question = (const float*)d_in[1];
  const float* Wg1      = (const float*)d_in[2];
  const float* bg1      = (const float*)d_in[3];
  const float* Wg2      = (const float*)d_in[4];
  const float* bg2      = (const float*)d_in[5];
  const float* Wf1      = (const float*)d_in[6];
  const float* bf1      = (const float*)d_in[7];
  const float* Wf2      = (const float*)d_in[8];
  const float* bf2      = (const float*)d_in[9];
  float* out = (float*)d_out;

  u16*   wsb  = (u16*)d_ws;
  u16*   Lqp  = wsb + LQ_U16;
  u16*   Rp   = wsb + R_U16;
  u16*   Bswz = wsb + BS_U16;
  float* Sp   = (float*)((char*)d_ws + S_BYTE);

  prep<<<512, 256, 0, stream>>>(image, question, Wg1, bg1, Wg2,
                                Lqp, Rp, Sp, Bswz);
  pair_gemm<<<256, 512, 0, stream>>>(Lqp, Rp, Bswz, bg2, Sp);
  final_mlp<<<NB, 256, 0, stream>>>(Sp, Wf1, bf1, Wf2, bf2, out);
}

// Round 19
// 105.491 us; speedup vs baseline: 1.6769x; 1.6769x over previous
//
#include <hip/hip_runtime.h>
#include <hip/hip_bf16.h>

// Problem constants
#define NB   32      // batch
#define NC   24      // image channels
#define ND   12      // spatial
#define NN   144     // ND*ND objects
#define QD   11
#define GH   256
#define FOUT 10

typedef unsigned short u16;
typedef _Float16 f16;
typedef __attribute__((ext_vector_type(8))) _Float16 f16x8;
typedef __attribute__((ext_vector_type(4))) float f32x4;

// Workspace layout (u16 units unless noted):
//   Lqh  u16 [32][144][256]  off 0          (= L + q@Wg1_q + bg1, f16)
//   Rh   u16 [32][144][256]  off 1179648
//   Bswz u16 [128][64][8]    off 2359296    (16x16x32 B-fragment order, f16)
//   S    f32 [32][256]       byte-off 4849664
#define LQ_U16  0
#define R_U16   1179648
#define BS_U16  2359296
#define S_BYTE  4849664

__device__ inline u16 f2h(float f) {
  f16 h = (f16)f;
  return *reinterpret_cast<u16*>(&h);
}

// ---------------------------------------------------------------------------
// prep v2 (r17-proven): Wg1 in registers; blocks [0,256) projections (f16
// out), blocks [256,512): Wg2 -> f16 B-fragment swizzle + zero S.
// ---------------------------------------------------------------------------
__global__ __launch_bounds__(256) void prep(const float* __restrict__ image,
                                            const float* __restrict__ question,
                                            const float* __restrict__ Wg1,
                                            const float* __restrict__ bg1,
                                            const float* __restrict__ Wg2,
                                            u16* __restrict__ Lq,
                                            u16* __restrict__ R,
                                            float* __restrict__ S,
                                            u16* __restrict__ Bswz) {
  int blk = blockIdx.x;
  int h   = threadIdx.x;
  if (blk < 256) {
    const int quarter = blk & 3;
    const int b       = (blk >> 2) & 31;
    const int which   = blk >> 7;
    float Wl[NC + 2];
#pragma unroll
    for (int r = 0; r < NC + 2; ++r)
      Wl[r] = Wg1[(which * (NC + 2) + r) * GH + h];
    float qacc = 0.f;
    if (which == 0) {
      qacc = bg1[h];
#pragma unroll
      for (int tq = 0; tq < QD; ++tq)
        qacc += question[b * QD + tq] * Wg1[(2 * (NC + 2) + tq) * GH + h];
    }
    const float* img = image + b * (NC * NN);
    u16* dst = (which == 0 ? Lq : R) + b * NN * GH + h;
    const float inv = 1.0f / (ND - 1);
#pragma unroll 4
    for (int p = quarter * 36; p < quarter * 36 + 36; ++p) {
      float acc = qacc;
#pragma unroll
      for (int c = 0; c < NC; ++c) acc += img[c * NN + p] * Wl[c];
      int i = p / ND, j = p - i * ND;
      acc += (j * inv) * Wl[24];
      acc += (i * inv) * Wl[25];
      dst[p * GH] = f2h(acc);
    }
  } else {
    int tid = (blk - 256) * 256 + h;   // 0..65535
    int e   = tid & 7;
    int l   = (tid >> 3) & 63;
    int fid = tid >> 9;
    int kt  = fid >> 4, nt = fid & 15;
    int k = kt * 32 + ((l >> 4) << 3) + e;
    int n = (nt << 4) + (l & 15);
    Bswz[tid] = f2h(Wg2[k * GH + n]);
    if (tid < NB * GH) S[tid] = 0.f;
  }
}

// ---------------------------------------------------------------------------
// MFMA pair GEMM v19 = v12/v17 structure with F16 end-to-end.
// Build math: v_pk_add_f16 + v_pk_max_f16 (8 VALU per 8 elems vs 36 for the
// bf16 decode path) -- the measured ~97k cyc/CU build VALU was the serial
// cost beside 100k MFMA. Same bytes as bf16 (no f32 L2 burst); f16 mantissa
// 10 bit > bf16 8 bit, MFMA accumulates f32.
// Block = 512 thr (8 waves, 2m x 4n), tile = 128 pairs x 256 cols.
// Per tile: [build | bar | mma + epi | bar]; XOR-swizzled A (0 conflicts);
// setprio around MFMA. Grid = 512 blocks (2/CU) XCD-pinned; ~10 tiles each.
// ---------------------------------------------------------------------------
__global__ __launch_bounds__(512, 2) void pair_gemm(const u16* __restrict__ Lq,
                                                    const u16* __restrict__ R,
                                                    const u16* __restrict__ Bswz,
                                                    const float* __restrict__ bg2,
                                                    float* __restrict__ S) {
  const int bid = blockIdx.x;          // 0..511
  const int xcd = bid & 7;
  const int idx = bid >> 3;            // 0..63
  const int b   = xcd * 4 + (idx >> 4);
  const int bi  = idx & 15;            // 16 blocks per batch, 162 tiles
  const int t0  = bi * 10 + (bi < 2 ? bi : 2);
  const int cnt = 10 + (bi < 2 ? 1 : 0);

  // [kt 8][mf 8][lane 64][8 f16] = 64 KB
  __shared__ __align__(16) u16 As[8 * 8 * 64 * 8];

  const int t = threadIdx.x;
  const int w = t >> 6, l = t & 63;
  const int wn = w & 3, wm = w >> 2;
  // builder role: row t>>2 (0..127), k-octet t&3
  const int brow = t >> 2;
  const int oc   = t & 3;
  const int mf_w   = brow >> 4;                              // 0..7
  const int lane_w = ((brow & 15) | (oc << 4)) ^ (oc << 1);  // 2-way (free)
  const int lane_r = l ^ (((l >> 4) & 3) << 1);

  const u16* Lbase = Lq + b * NN * GH;
  const u16* Rbase = R + b * NN * GH;
  const u16* Bl    = Bswz + l * 8;

  float bgv[4];
#pragma unroll
  for (int nt = 0; nt < 4; ++nt)
    bgv[nt] = bg2[(wn << 6) + (nt << 4) + (l & 15)];
  float ssum[4] = {0.f, 0.f, 0.f, 0.f};

  for (int tt = 0; tt < cnt; ++tt) {
    // ---- build phase: whole 128x256 tile into LDS (pk f16 math) ----
    {
      int p = (t0 + tt) * 128 + brow;
      int i = p / NN, j = p - i * NN;
      const u16* Lr = Lbase + i * GH + oc * 8;
      const u16* Rr = Rbase + j * GH + oc * 8;
#pragma unroll
      for (int half = 0; half < 2; ++half) {
        f16x8 lv[4], rv[4];
#pragma unroll
        for (int q = 0; q < 4; ++q) {
          lv[q] = *(const f16x8*)(Lr + ((half << 2) | q) * 32);
          rv[q] = *(const f16x8*)(Rr + ((half << 2) | q) * 32);
        }
#pragma unroll
        for (int q = 0; q < 4; ++q) {
          const int kt = (half << 2) | q;
          f16x8 s = lv[q] + rv[q];                       // v_pk_add_f16
          s = __builtin_elementwise_max(s, (f16x8)0.0f); // v_pk_max_f16
          *(f16x8*)&As[((((kt << 3) | mf_w) << 6) | lane_w) << 3] = s;
        }
      }
    }
    __syncthreads();

    // ---- MFMA phase ----
    f32x4 acc[4][4] = {};
#pragma unroll
    for (int kt = 0; kt < 8; ++kt) {
      f16x8 af[4];
#pragma unroll
      for (int mf = 0; mf < 4; ++mf)
        af[mf] = *(const f16x8*)
            &As[((((kt << 3) | (wm << 2) | mf) << 6) | lane_r) << 3];
      f16x8 bfr[4];
#pragma unroll
      for (int nt = 0; nt < 4; ++nt) {
        int fid = (kt << 4) | (wn << 2) | nt;
        bfr[nt] = *(const f16x8*)(Bl + ((size_t)fid << 9));
      }
      __builtin_amdgcn_s_setprio(1);
#pragma unroll
      for (int mf = 0; mf < 4; ++mf)
#pragma unroll
        for (int nt = 0; nt < 4; ++nt)
          acc[mf][nt] = __builtin_amdgcn_mfma_f32_16x16x32_f16(
              af[mf], bfr[nt], acc[mf][nt], 0, 0, 0);
      __builtin_amdgcn_s_setprio(0);
    }
    // epilogue: fold relu(acc + bg2) into running sums
#pragma unroll
    for (int nt = 0; nt < 4; ++nt) {
      float s = 0.f;
#pragma unroll
      for (int mf = 0; mf < 4; ++mf)
#pragma unroll
        for (int r = 0; r < 4; ++r) {
          float v = acc[mf][nt][r] + bgv[nt];
          s += v > 0.f ? v : 0.f;
        }
      ssum[nt] += s;
    }
    __syncthreads();
  }

  // Final reduce: C/D col = l&15; shfl-reduce rows, one atomic per col slice
  float* Sb = S + b * GH;
#pragma unroll
  for (int nt = 0; nt < 4; ++nt) {
    float s = ssum[nt];
    s += __shfl_xor(s, 16, 64);
    s += __shfl_xor(s, 32, 64);
    if (l < 16) atomicAdd(&Sb[(wn << 6) + (nt << 4) + l], s);
  }
}

// ---------------------------------------------------------------------------
// Final f-MLP: out = relu(S@Wf1+bf1)@Wf2+bf2. One block per batch.
// ---------------------------------------------------------------------------
__global__ __launch_bounds__(256) void final_mlp(const float* __restrict__ S,
                                                 const float* __restrict__ Wf1,
                                                 const float* __restrict__ bf1,
                                                 const float* __restrict__ Wf2,
                                                 const float* __restrict__ bf2,
                                                 float* __restrict__ out) {
  __shared__ float sS[GH];
  __shared__ float oS[GH];
  int b = blockIdx.x, h = threadIdx.x;
  sS[h] = S[b * GH + h];
  __syncthreads();
  float acc = bf1[h];
#pragma unroll 8
  for (int k = 0; k < GH; ++k) acc += sS[k] * Wf1[k * GH + h];
  oS[h] = acc > 0.f ? acc : 0.f;
  __syncthreads();
  if (h < FOUT) {
    float o = bf2[h];
#pragma unroll 8
    for (int k = 0; k < GH; ++k) o += oS[k] * Wf2[k * FOUT + h];
    out[b * FOUT + h] = o;
  }
}

extern "C" void kernel_launch(void* const* d_in, const int* in_sizes, int n_in,
                              void* d_out, int out_size, void* d_ws, size_t ws_size,
                              hipStream_t stream) {
  const float* image    = (const float*)d_in[0];
  const float* question = (const float*)d_in[1];
  const float* Wg1      = (const float*)d_in[2];
  const float* bg1      = (const float*)d_in[3];
  const float* Wg2      = (const float*)d_in[4];
  const float* bg2      = (const float*)d_in[5];
  const float* Wf1      = (const float*)d_in[6];
  const float* bf1      = (const float*)d_in[7];
  const float* Wf2      = (const float*)d_in[8];
  const float* bf2      = (const float*)d_in[9];
  float* out = (float*)d_out;

  u16*   wsb  = (u16*)d_ws;
  u16*   Lqp  = wsb + LQ_U16;
  u16*   Rp   = wsb + R_U16;
  u16*   Bswz = wsb + BS_U16;
  float* Sp   = (float*)((char*)d_ws + S_BYTE);

  prep<<<512, 256, 0, stream>>>(image, question, Wg1, bg1, Wg2,
                                Lqp, Rp, Sp, Bswz);
  pair_gemm<<<512, 512, 0, stream>>>(Lqp, Rp, Bswz, bg2, Sp);
  final_mlp<<<NB, 256, 0, stream>>>(Sp, Wf1, bf1, Wf2, bf2, out);
}